// Round 4
// baseline (281.434 us; speedup 1.0000x reference)
//
#include <hip/hip_runtime.h>
#include <math.h>

// Problem constants (from reference): B=4, S=2048, n_head=32, h_dim=128
// Dtype map (established rounds 0-3): ALL inputs fp32, output fp32.
// (Harness compares in bf16 domain, but buffers are fp32.)
#define SEQ_LEN 2048
#define NROWS (4 * 2048 * 32)      // 262144 head-rows of 128
#define NSTRIPS (NROWS / 16)       // 16384 strips of 16 rows

typedef short bf16x8 __attribute__((ext_vector_type(8)));  // 8 bf16 = 4 VGPR (MFMA A/B frag)
typedef float f32x4 __attribute__((ext_vector_type(4)));   // MFMA C/D frag

__device__ __forceinline__ unsigned short f2bf(float f) {
    union { float f; unsigned int i; } v; v.f = f;
    unsigned int r = v.i + 0x7FFFu + ((v.i >> 16) & 1u);  // round-to-nearest-even
    return (unsigned short)(r >> 16);
}

// ---------------------------------------------------------------------------
// prep: M = A_0 * A_1 * ... * A_63 * R  (y = x @ M), built in fp32 LDS,
// then rounded to bf16 and stored pre-swizzled in 16x16x32 B-fragment order:
// frag f = kk*8+nt, lane l holds B[k = kk*32 + (l>>4)*8 + j][n = nt*16 + (l&15)]
// ---------------------------------------------------------------------------
__global__ void prep_kernel(const float* __restrict__ thetas,
                            const float* __restrict__ pairs,
                            const float* __restrict__ tscale,
                            const float* __restrict__ rotmat,
                            unsigned short* __restrict__ Bsw) {
    __shared__ float M[128][128];   // 64 KB
    const int t = threadIdx.x;      // 128 threads, thread t owns column t
    for (int d = 0; d < 128; ++d) M[d][t] = rotmat[d * 128 + t];
    const float scale = tscale[0];
    // Left-mult by A_r for r = 63 down to 0. Givens left-mult touches only
    // rows i,j of M -> column-private per thread, no syncs needed.
    for (int r = 63; r >= 0; --r) {
        int i = (int)pairs[2 * r];
        int j = (int)pairs[2 * r + 1];
        i = min(max(i, 0), 127); j = min(max(j, 0), 127);
        const float th = thetas[r] * scale;
        const float c = cosf(th), s = sinf(th);
        if (i == j) {
            M[i][t] *= c;
        } else {
            const float a = M[i][t], b = M[j][t];
            M[i][t] = c * a - s * b;   // (A M)[i,:] = c*M[i,:] - s*M[j,:]
            M[j][t] = s * a + c * b;   // (A M)[j,:] = s*M[i,:] + c*M[j,:]
        }
    }
    __syncthreads();
    for (int idx = t; idx < 32 * 64; idx += 128) {
        const int f = idx >> 6, lane = idx & 63;
        const int kk = f >> 3, nt = f & 7;
        const int krow = kk * 32 + (lane >> 4) * 8;
        const int col = nt * 16 + (lane & 15);
        unsigned short* dst = Bsw + (size_t)idx * 8;
#pragma unroll
        for (int j2 = 0; j2 < 8; ++j2) dst[j2] = f2bf(M[krow + j2][col]);
    }
}

// ---------------------------------------------------------------------------
// main: per wave, grid-stride over 16-row strips of x (fp32).
// y = x_strip(16x128) @ M(128x128) via 4 K-steps x 8 N-tiles of 16x16x32 MFMA
// (x rounded to bf16 in-register, fp32 accumulate), then fused RoPE epilogue:
// out[k] = y[2k]*cos - y[2k+1]*sin ; out[64+k] = y[2k]*sin + y[2k+1]*cos,
// angle = s * inv_freq[k]. B fully register-resident (128 VGPR); no LDS.
// Output stored as fp32.
// ---------------------------------------------------------------------------
__global__ __launch_bounds__(256) void rope_kernel(
        const float* __restrict__ x,
        const unsigned short* __restrict__ Bsw,
        const float* __restrict__ invfreq,
        float* __restrict__ out) {
    const int lane = threadIdx.x & 63;
    const int wave = (int)(blockIdx.x * (blockDim.x >> 6) + (threadIdx.x >> 6));
    const int nwaves = (int)(gridDim.x * (blockDim.x >> 6));
    const int m = lane & 15;
    const int quad = lane >> 4;

    bf16x8 Bf[32];
    const bf16x8* Bp = (const bf16x8*)Bsw;
#pragma unroll
    for (int f = 0; f < 32; ++f) Bf[f] = Bp[f * 64 + lane];

    const float invf = invfreq[lane];  // lane k <-> frequency k (64 freqs)
    const int kq = m >> 1;
    const bool oddl = (m & 1);

    for (int strip = wave; strip < NSTRIPS; strip += nwaves) {
        const int r0 = strip * 16;
        const float* xrow = x + (size_t)(r0 + m) * 128 + quad * 8;
        bf16x8 A[4];
#pragma unroll
        for (int kk = 0; kk < 4; ++kk) {
            const f32x4 lo = *(const f32x4*)(xrow + kk * 32);
            const f32x4 hi = *(const f32x4*)(xrow + kk * 32 + 4);
            bf16x8 a;
#pragma unroll
            for (int e = 0; e < 4; ++e) {
                a[e]     = (short)f2bf(lo[e]);
                a[e + 4] = (short)f2bf(hi[e]);
            }
            A[kk] = a;
        }

        // all 16 rows of the strip share one sequence position s
        const int s_pos = (r0 >> 5) & (SEQ_LEN - 1);
        float sn_l, cs_l;
        sincosf((float)s_pos * invf, &sn_l, &cs_l);  // lane k holds sin/cos for freq k

        f32x4 acc[8];
#pragma unroll
        for (int nt = 0; nt < 8; ++nt) acc[nt] = (f32x4){0.f, 0.f, 0.f, 0.f};

#pragma unroll
        for (int kk = 0; kk < 4; ++kk) {
#pragma unroll
            for (int nt = 0; nt < 8; ++nt)
                acc[nt] = __builtin_amdgcn_mfma_f32_16x16x32_bf16(
                    A[kk], Bf[kk * 8 + nt], acc[nt], 0, 0, 0);
        }

        // epilogue: C/D layout col = nt*16 + (lane&15), row = quad*4 + reg
        float* orow = out + (size_t)r0 * 128;
#pragma unroll
        for (int nt = 0; nt < 8; ++nt) {
            const int k = nt * 8 + kq;
            const float c = __shfl(cs_l, k, 64);
            const float sn = __shfl(sn_l, k, 64);
            const float ss = oddl ? sn : -sn;
            const int outcol = oddl ? (64 + k) : k;
#pragma unroll
            for (int rr = 0; rr < 4; ++rr) {
                const float v = acc[nt][rr];                 // my y (even: y[2k], odd: y[2k+1])
                const float p = __shfl_xor(v, 1, 64);        // partner's y
                const float val = fmaf(p, ss, v * c);        // even: v*c - p*sn ; odd: v*c + p*sn
                orow[(size_t)(quad * 4 + rr) * 128 + outcol] = val;
            }
        }
    }
}

extern "C" void kernel_launch(void* const* d_in, const int* in_sizes, int n_in,
                              void* d_out, int out_size, void* d_ws, size_t ws_size,
                              hipStream_t stream) {
    const float* x      = (const float*)d_in[0];   // fp32
    const float* thetas = (const float*)d_in[1];   // fp32
    const float* pairs  = (const float*)d_in[2];   // fp32
    const float* tscale = (const float*)d_in[3];   // fp32
    const float* rotmat = (const float*)d_in[4];   // fp32
    const float* invfr  = (const float*)d_in[5];   // fp32
    // d_in[6] = n_head (int, ==32) — baked into constants
    float* out = (float*)d_out;                    // fp32
    unsigned short* Bsw = (unsigned short*)d_ws;   // 32 KB used

    prep_kernel<<<1, 128, 0, stream>>>(thetas, pairs, tscale, rotmat, Bsw);
    rope_kernel<<<1024, 256, 0, stream>>>(x, Bsw, invfr, out);
}